// Round 1
// baseline (9198.859 us; speedup 1.0000x reference)
//
#include <hip/hip_runtime.h>
#include <hip/hip_bf16.h>

#define N_NODES 50000
#define N_EDGES 800000
#define HIDDEN  256
#define N_LAYERS 3
#define N_PAIRS 4096
#define N_LABEL (N_PAIRS * 2)   // 8192 labeled rows

// ---------------------------------------------------------------------------
// Linear kernel: C[row] = A[row] @ W + b for 16 rows per block.
// 256 threads: thread c owns output column c for all 16 rows.
// INDEXED=true: rows gathered/scattered through idx (labeled-row overwrite).
// ---------------------------------------------------------------------------
template <bool INDEXED>
__global__ __launch_bounds__(256) void linear_kernel(
    const float* __restrict__ A,    // (N_NODES, HIDDEN) source matrix
    const float* __restrict__ W,    // (HIDDEN, HIDDEN) row-major [k][c]
    const float* __restrict__ bias, // (HIDDEN)
    float* __restrict__ C,          // output rows (scatter if INDEXED)
    const int* __restrict__ idx,    // row ids if INDEXED, else nullptr
    int nrows)
{
    constexpr int R = 16;
    __shared__ float xs[R][HIDDEN];   // 16 KB
    __shared__ int rowid[R];

    const int c  = threadIdx.x;
    const int r0 = blockIdx.x * R;

    if (c < R) {
        int r = r0 + c;
        int rid = -1;
        if (r < nrows) rid = INDEXED ? idx[r] : r;
        rowid[c] = rid;
    }
    __syncthreads();

    // stage the 16 source rows into LDS (coalesced per row)
    #pragma unroll
    for (int r = 0; r < R; ++r) {
        int rid = rowid[r];
        xs[r][c] = (rid >= 0) ? A[(size_t)rid * HIDDEN + c] : 0.f;
    }
    __syncthreads();

    float acc[R];
    const float b = bias[c];
    #pragma unroll
    for (int r = 0; r < R; ++r) acc[r] = b;

    // k-loop: 4 W-row loads (coalesced, L2-resident) + LDS-broadcast float4 x
    for (int k = 0; k < HIDDEN; k += 4) {
        const float w0 = W[(size_t)(k + 0) * HIDDEN + c];
        const float w1 = W[(size_t)(k + 1) * HIDDEN + c];
        const float w2 = W[(size_t)(k + 2) * HIDDEN + c];
        const float w3 = W[(size_t)(k + 3) * HIDDEN + c];
        #pragma unroll
        for (int r = 0; r < R; ++r) {
            const float4 xv = *(const float4*)&xs[r][k];
            acc[r] += xv.x * w0 + xv.y * w1 + xv.z * w2 + xv.w * w3;
        }
    }

    #pragma unroll
    for (int r = 0; r < R; ++r) {
        int rid = rowid[r];
        if (rid >= 0) C[(size_t)rid * HIDDEN + c] = acc[r];
    }
}

// ---------------------------------------------------------------------------
// Edge-parallel scatter-add: out[dst[e]] += h[src[e]].  64 lanes per edge,
// float4 per lane (4 atomics). 4 edges per 256-thread block.
// ---------------------------------------------------------------------------
__global__ __launch_bounds__(256) void scatter_add_kernel(
    const float* __restrict__ h,
    const int* __restrict__ src,
    const int* __restrict__ dst,
    float* __restrict__ out)
{
    const int e = blockIdx.x * 4 + (threadIdx.x >> 6);
    if (e >= N_EDGES) return;
    const int lane = threadIdx.x & 63;
    const int s = src[e];
    const int d = dst[e];
    const float4 v = *(const float4*)&h[(size_t)s * HIDDEN + lane * 4];
    float* o = &out[(size_t)d * HIDDEN + lane * 4];
    atomicAdd(o + 0, v.x);
    atomicAdd(o + 1, v.y);
    atomicAdd(o + 2, v.z);
    atomicAdd(o + 3, v.w);
}

// ---------------------------------------------------------------------------
// Final gather: out[i] = x[pos_flat[i]] for i in [0, 8192)
// ---------------------------------------------------------------------------
__global__ __launch_bounds__(256) void gather_kernel(
    const float* __restrict__ x,
    const int* __restrict__ pos,
    float* __restrict__ out)
{
    const int i = blockIdx.x;
    const int c = threadIdx.x;
    const int node = pos[i];
    out[(size_t)i * HIDDEN + c] = x[(size_t)node * HIDDEN + c];
}

extern "C" void kernel_launch(void* const* d_in, const int* in_sizes, int n_in,
                              void* d_out, int out_size, void* d_ws, size_t ws_size,
                              hipStream_t stream)
{
    const float* x       = (const float*)d_in[0];
    const float* f0_w    = (const float*)d_in[1];
    const float* f0_b    = (const float*)d_in[2];
    const float* f1_w    = (const float*)d_in[3];
    const float* f1_b    = (const float*)d_in[4];
    const float* conv_w  = (const float*)d_in[5];
    const float* conv_b  = (const float*)d_in[6];
    const int*   edge_src = (const int*)d_in[7];
    const int*   edge_dst = (const int*)d_in[8];
    const int*   pos      = (const int*)d_in[9];
    float* out = (float*)d_out;

    const size_t buf_elems = (size_t)N_NODES * HIDDEN;      // 12.8M floats
    float* ws0 = (float*)d_ws;                              // x0 buffer
    float* ws1 = ws0 + buf_elems;                           // h buffer
    float* ws2 = ws1 + buf_elems;                           // x / xnext buffer

    const int gemm_blocks  = N_NODES / 16;   // 3125
    const int label_blocks = N_LABEL / 16;   // 512
    const int scat_blocks  = N_EDGES / 4;    // 200000

    const float* x_cur = x;
    for (int l = 0; l < N_LAYERS; ++l) {
        const float* W0 = f0_w  + (size_t)l * HIDDEN * HIDDEN;
        const float* B0 = f0_b  + (size_t)l * HIDDEN;
        const float* W1 = f1_w  + (size_t)l * HIDDEN * HIDDEN;
        const float* B1 = f1_b  + (size_t)l * HIDDEN;
        const float* Wc = conv_w + (size_t)l * HIDDEN * HIDDEN;
        const float* Bc = conv_b + (size_t)l * HIDDEN;

        // x0 = x @ F0 + b0   (all nodes)
        linear_kernel<false><<<gemm_blocks, 256, 0, stream>>>(
            x_cur, W0, B0, ws0, nullptr, N_NODES);
        // x0[idx] = x[idx] @ F1 + b1  (overwrite labeled rows; dup idx benign)
        linear_kernel<true><<<label_blocks, 256, 0, stream>>>(
            x_cur, W1, B1, ws0, pos, N_LABEL);
        // h = x0 @ Cw + cb
        linear_kernel<false><<<gemm_blocks, 256, 0, stream>>>(
            ws0, Wc, Bc, ws1, nullptr, N_NODES);
        // xnext = segment_sum(h[src], dst)  — x_cur (==ws2 for l>0) is dead now
        hipMemsetAsync(ws2, 0, buf_elems * sizeof(float), stream);
        scatter_add_kernel<<<scat_blocks, 256, 0, stream>>>(
            ws1, edge_src, edge_dst, ws2);

        x_cur = ws2;
    }

    // out = x[pos]  -> (4096, 2, 256) flattened
    gather_kernel<<<N_LABEL, 256, 0, stream>>>(ws2, pos, out);
}

// Round 2
// 1586.052 us; speedup vs baseline: 5.7998x; 5.7998x over previous
//
#include <hip/hip_runtime.h>
#include <hip/hip_bf16.h>

#define N_NODES 50000
#define N_EDGES 800000
#define HIDDEN  256
#define N_LAYERS 3
#define N_PAIRS 4096
#define N_LABEL (N_PAIRS * 2)   // 8192 labeled rows
#define NPAD    50176           // 196*256, padded node count for the scan
#define SCAN_BLOCKS (NPAD / 256) // 196

// ---------------------------------------------------------------------------
// Linear kernel: C[row] = A[row] @ W + b for 16 rows per block.
// 256 threads: thread c owns output column c for all 16 rows.
// INDEXED=true: rows gathered/scattered through idx (labeled-row overwrite).
// ---------------------------------------------------------------------------
template <bool INDEXED>
__global__ __launch_bounds__(256) void linear_kernel(
    const float* __restrict__ A,
    const float* __restrict__ W,    // (HIDDEN, HIDDEN) row-major [k][c]
    const float* __restrict__ bias,
    float* __restrict__ C,
    const int* __restrict__ idx,
    int nrows)
{
    constexpr int R = 16;
    __shared__ float xs[R][HIDDEN];
    __shared__ int rowid[R];

    const int c  = threadIdx.x;
    const int r0 = blockIdx.x * R;

    if (c < R) {
        int r = r0 + c;
        int rid = -1;
        if (r < nrows) rid = INDEXED ? idx[r] : r;
        rowid[c] = rid;
    }
    __syncthreads();

    #pragma unroll
    for (int r = 0; r < R; ++r) {
        int rid = rowid[r];
        xs[r][c] = (rid >= 0) ? A[(size_t)rid * HIDDEN + c] : 0.f;
    }
    __syncthreads();

    float acc[R];
    const float b = bias[c];
    #pragma unroll
    for (int r = 0; r < R; ++r) acc[r] = b;

    for (int k = 0; k < HIDDEN; k += 4) {
        const float w0 = W[(size_t)(k + 0) * HIDDEN + c];
        const float w1 = W[(size_t)(k + 1) * HIDDEN + c];
        const float w2 = W[(size_t)(k + 2) * HIDDEN + c];
        const float w3 = W[(size_t)(k + 3) * HIDDEN + c];
        #pragma unroll
        for (int r = 0; r < R; ++r) {
            const float4 xv = *(const float4*)&xs[r][k];
            acc[r] += xv.x * w0 + xv.y * w1 + xv.z * w2 + xv.w * w3;
        }
    }

    #pragma unroll
    for (int r = 0; r < R; ++r) {
        int rid = rowid[r];
        if (rid >= 0) C[(size_t)rid * HIDDEN + c] = acc[r];
    }
}

// ---------------------------------------------------------------------------
// CSR build: histogram -> 2-level exclusive scan -> cursor fill
// ---------------------------------------------------------------------------
__global__ __launch_bounds__(256) void hist_kernel(
    const int* __restrict__ dst, int* __restrict__ counts)
{
    int e = blockIdx.x * 256 + threadIdx.x;
    if (e < N_EDGES) atomicAdd(&counts[dst[e]], 1);
}

__device__ __forceinline__ int block_incl_scan(int v, int* s, int t)
{
    s[t] = v; __syncthreads();
    #pragma unroll
    for (int off = 1; off < 256; off <<= 1) {
        int add = (t >= off) ? s[t - off] : 0;
        __syncthreads();
        s[t] += add;
        __syncthreads();
    }
    return s[t];
}

__global__ __launch_bounds__(256) void scan1_kernel(
    const int* __restrict__ counts, int* __restrict__ excl, int* __restrict__ bsum)
{
    __shared__ int s[256];
    const int t = threadIdx.x;
    const int i = blockIdx.x * 256 + t;
    const int v = counts[i];
    int incl = block_incl_scan(v, s, t);
    excl[i] = incl - v;
    if (t == 255) bsum[blockIdx.x] = incl;
}

__global__ __launch_bounds__(256) void scan2_kernel(
    const int* __restrict__ bsum, int* __restrict__ bbase)
{
    __shared__ int s[256];
    const int t = threadIdx.x;
    const int v = (t < SCAN_BLOCKS) ? bsum[t] : 0;
    int incl = block_incl_scan(v, s, t);
    bbase[t] = incl - v;
}

__global__ __launch_bounds__(256) void scan3_kernel(
    const int* __restrict__ excl, const int* __restrict__ bbase,
    int* __restrict__ offs, int* __restrict__ cursor)
{
    const int i = blockIdx.x * 256 + threadIdx.x;
    const int o = excl[i] + bbase[blockIdx.x];
    offs[i] = o;
    cursor[i] = o;
}

__global__ __launch_bounds__(256) void fill_kernel(
    const int* __restrict__ src, const int* __restrict__ dst,
    int* __restrict__ cursor, int* __restrict__ src_sorted)
{
    int e = blockIdx.x * 256 + threadIdx.x;
    if (e < N_EDGES) {
        int p = atomicAdd(&cursor[dst[e]], 1);
        src_sorted[p] = src[e];
    }
}

// ---------------------------------------------------------------------------
// Pull-mode segment sum: out[d] = sum over in-edges of h[src]. One block per
// dst node; thread c owns column c. Coalesced 1 KB row reads, no atomics.
// ---------------------------------------------------------------------------
__global__ __launch_bounds__(256) void seg_sum_kernel(
    const float* __restrict__ h,
    const int* __restrict__ srcs,
    const int* __restrict__ offs,
    float* __restrict__ out)
{
    const int d = blockIdx.x;
    const int c = threadIdx.x;
    const int beg = offs[d];
    const int end = offs[d + 1];

    float acc = 0.f;
    int j = beg;
    for (; j + 4 <= end; j += 4) {
        const int s0 = srcs[j + 0], s1 = srcs[j + 1];
        const int s2 = srcs[j + 2], s3 = srcs[j + 3];
        const float a0 = h[(size_t)s0 * HIDDEN + c];
        const float a1 = h[(size_t)s1 * HIDDEN + c];
        const float a2 = h[(size_t)s2 * HIDDEN + c];
        const float a3 = h[(size_t)s3 * HIDDEN + c];
        acc += a0 + a1 + a2 + a3;
    }
    for (; j < end; ++j) acc += h[(size_t)srcs[j] * HIDDEN + c];

    out[(size_t)d * HIDDEN + c] = acc;
}

// ---------------------------------------------------------------------------
// Final gather: out[i] = x[pos_flat[i]]
// ---------------------------------------------------------------------------
__global__ __launch_bounds__(256) void gather_kernel(
    const float* __restrict__ x,
    const int* __restrict__ pos,
    float* __restrict__ out)
{
    const int i = blockIdx.x;
    const int c = threadIdx.x;
    const int node = pos[i];
    out[(size_t)i * HIDDEN + c] = x[(size_t)node * HIDDEN + c];
}

extern "C" void kernel_launch(void* const* d_in, const int* in_sizes, int n_in,
                              void* d_out, int out_size, void* d_ws, size_t ws_size,
                              hipStream_t stream)
{
    const float* x       = (const float*)d_in[0];
    const float* f0_w    = (const float*)d_in[1];
    const float* f0_b    = (const float*)d_in[2];
    const float* f1_w    = (const float*)d_in[3];
    const float* f1_b    = (const float*)d_in[4];
    const float* conv_w  = (const float*)d_in[5];
    const float* conv_b  = (const float*)d_in[6];
    const int*   edge_src = (const int*)d_in[7];
    const int*   edge_dst = (const int*)d_in[8];
    const int*   pos      = (const int*)d_in[9];
    float* out = (float*)d_out;

    const size_t buf_elems = (size_t)N_NODES * HIDDEN;
    float* ws0 = (float*)d_ws;          // x0
    float* ws1 = ws0 + buf_elems;       // h
    float* ws2 = ws1 + buf_elems;       // x / xnext

    // CSR scratch (~4 MB) after the float buffers
    int* counts     = (int*)(ws2 + buf_elems);   // NPAD
    int* excl       = counts + NPAD;             // NPAD
    int* bsum       = excl + NPAD;               // 256
    int* bbase      = bsum + 256;                // 256
    int* offs       = bbase + 256;               // NPAD (offs[50000] valid)
    int* cursor     = offs + NPAD;               // NPAD
    int* src_sorted = cursor + NPAD;             // N_EDGES

    const int edge_blocks  = (N_EDGES + 255) / 256;  // 3125
    const int gemm_blocks  = N_NODES / 16;           // 3125
    const int label_blocks = N_LABEL / 16;           // 512

    // ---- Build CSR once per launch (edges are layer-invariant) ----
    hipMemsetAsync(counts, 0, NPAD * sizeof(int), stream);
    hist_kernel<<<edge_blocks, 256, 0, stream>>>(edge_dst, counts);
    scan1_kernel<<<SCAN_BLOCKS, 256, 0, stream>>>(counts, excl, bsum);
    scan2_kernel<<<1, 256, 0, stream>>>(bsum, bbase);
    scan3_kernel<<<SCAN_BLOCKS, 256, 0, stream>>>(excl, bbase, offs, cursor);
    fill_kernel<<<edge_blocks, 256, 0, stream>>>(edge_src, edge_dst, cursor, src_sorted);

    // ---- Layers ----
    const float* x_cur = x;
    for (int l = 0; l < N_LAYERS; ++l) {
        const float* W0 = f0_w  + (size_t)l * HIDDEN * HIDDEN;
        const float* B0 = f0_b  + (size_t)l * HIDDEN;
        const float* W1 = f1_w  + (size_t)l * HIDDEN * HIDDEN;
        const float* B1 = f1_b  + (size_t)l * HIDDEN;
        const float* Wc = conv_w + (size_t)l * HIDDEN * HIDDEN;
        const float* Bc = conv_b + (size_t)l * HIDDEN;

        linear_kernel<false><<<gemm_blocks, 256, 0, stream>>>(
            x_cur, W0, B0, ws0, nullptr, N_NODES);
        linear_kernel<true><<<label_blocks, 256, 0, stream>>>(
            x_cur, W1, B1, ws0, pos, N_LABEL);
        linear_kernel<false><<<gemm_blocks, 256, 0, stream>>>(
            ws0, Wc, Bc, ws1, nullptr, N_NODES);
        // xnext = pull-mode segment sum (writes every row; no memset needed)
        seg_sum_kernel<<<N_NODES, 256, 0, stream>>>(ws1, src_sorted, offs, ws2);

        x_cur = ws2;
    }

    gather_kernel<<<N_LABEL, 256, 0, stream>>>(ws2, pos, out);
}

// Round 3
// 707.002 us; speedup vs baseline: 13.0111x; 2.2433x over previous
//
#include <hip/hip_runtime.h>
#include <hip/hip_bf16.h>

#define N_NODES 50000
#define N_EDGES 800000
#define HIDDEN  256
#define N_LAYERS 3
#define N_PAIRS 4096
#define N_LABEL 8192            // 2*N_PAIRS labeled rows
#define NPAD    50176           // 196*256, padded node count for the scan
#define SCAN_BLOCKS (NPAD / 256) // 196

typedef __bf16 bf16x8 __attribute__((ext_vector_type(8)));
typedef __bf16 bf16x4 __attribute__((ext_vector_type(4)));
typedef float  f32x4  __attribute__((ext_vector_type(4)));

__device__ __forceinline__ void load_lds16(const void* g, void* l) {
    __builtin_amdgcn_global_load_lds(
        (const __attribute__((address_space(1))) void*)g,
        (__attribute__((address_space(3))) void*)l, 16, 0, 0);
}

// ---------------------------------------------------------------------------
// MFMA GEMM: C[row] = A[row] @ W + b, A bf16 (N,256), Wt bf16 transposed
// [n][k].  128x128 tile, BK=32, 4 waves of 4x4 16x16x32 fragments.
// INDEXED: A-rows gathered and C-rows scattered through idx (dup idx write
// identical data -> benign).  OUT_BF16 selects output dtype.
// ---------------------------------------------------------------------------
template <bool INDEXED, bool OUT_BF16>
__global__ __launch_bounds__(256) void mfma_gemm(
    const __bf16* __restrict__ A,
    const __bf16* __restrict__ Wt,    // (256,256) bf16, Wt[n][k]
    const float* __restrict__ bias,   // (256) fp32
    void* __restrict__ Cout,
    const int* __restrict__ idx,
    int M)
{
    __shared__ __bf16 As[128 * 32];   // [row][k] 8 KB
    __shared__ __bf16 Bs[128 * 32];   // [n][k]   8 KB
    __shared__ int s_idx[128];

    const int t    = threadIdx.x;
    const int lane = t & 63;
    const int wave = t >> 6;
    const int m0   = blockIdx.x * 128;
    const int n0   = blockIdx.y * 128;

    if constexpr (INDEXED) {
        if (t < 128) s_idx[t] = idx[m0 + t];
        __syncthreads();
    }

    // staging pointers: chunk c = r*256 + t; row = c>>2, col8 = (c&3)*8
    // LDS dest offset = c*16 bytes (wave-uniform base + lane*16: m104-safe)
    const __bf16* aptr[2];
    const __bf16* bptr[2];
    #pragma unroll
    for (int r = 0; r < 2; ++r) {
        const int c    = r * 256 + t;
        const int row  = c >> 2;
        const int col8 = (c & 3) * 8;
        int node;
        if constexpr (INDEXED) {
            node = s_idx[row];
        } else {
            const int rg = m0 + row;
            node = (rg < M) ? rg : (M - 1);   // clamp; stores guarded below
        }
        aptr[r] = A  + (size_t)node * HIDDEN + col8;
        bptr[r] = Wt + (size_t)(n0 + row) * HIDDEN + col8;
    }

    f32x4 acc[16];
    #pragma unroll
    for (int i = 0; i < 16; ++i) acc[i] = (f32x4){0.f, 0.f, 0.f, 0.f};

    const int wm   = (wave & 1) * 64;
    const int wn   = (wave >> 1) * 64;
    const int fm   = lane & 15;
    const int quad = lane >> 4;

    for (int k0 = 0; k0 < HIDDEN; k0 += 32) {
        __syncthreads();   // previous iter's LDS reads complete
        #pragma unroll
        for (int r = 0; r < 2; ++r) {
            load_lds16(aptr[r] + k0, (void*)(As + (size_t)(r * 256 + t) * 8));
            load_lds16(bptr[r] + k0, (void*)(Bs + (size_t)(r * 256 + t) * 8));
        }
        __syncthreads();   // drains vmcnt(0): global_load_lds data visible

        bf16x8 af[4], bfr[4];
        #pragma unroll
        for (int mt = 0; mt < 4; ++mt)
            af[mt] = *(const bf16x8*)(As + (wm + mt * 16 + fm) * 32 + quad * 8);
        #pragma unroll
        for (int nt = 0; nt < 4; ++nt)
            bfr[nt] = *(const bf16x8*)(Bs + (wn + nt * 16 + fm) * 32 + quad * 8);

        #pragma unroll
        for (int mt = 0; mt < 4; ++mt)
            #pragma unroll
            for (int nt = 0; nt < 4; ++nt)
                acc[mt * 4 + nt] = __builtin_amdgcn_mfma_f32_16x16x32_bf16(
                    af[mt], bfr[nt], acc[mt * 4 + nt], 0, 0, 0);
    }

    // epilogue: C/D layout col=lane&15, row=quad*4+reg (m89/m91-verified)
    float bb[4];
    #pragma unroll
    for (int nt = 0; nt < 4; ++nt) bb[nt] = bias[n0 + wn + nt * 16 + fm];

    #pragma unroll
    for (int mt = 0; mt < 4; ++mt) {
        const int rbase = wm + mt * 16 + quad * 4;
        #pragma unroll
        for (int rg = 0; rg < 4; ++rg) {
            const int rloc = rbase + rg;
            int orow;
            if constexpr (INDEXED) {
                orow = s_idx[rloc];
            } else {
                orow = m0 + rloc;
                if (orow >= M) continue;
            }
            #pragma unroll
            for (int nt = 0; nt < 4; ++nt) {
                const int col = n0 + wn + nt * 16 + fm;
                const float v = acc[mt * 4 + nt][rg] + bb[nt];
                if constexpr (OUT_BF16)
                    ((__bf16*)Cout)[(size_t)orow * HIDDEN + col] = (__bf16)v;
                else
                    ((float*)Cout)[(size_t)orow * HIDDEN + col] = v;
            }
        }
    }
}

// ---------------------------------------------------------------------------
// Weight transpose+convert for one layer: T[n][k] = (bf16)W[k][n], 3 tensors.
// grid (8,8,3) tiles of 32x32, block (32,8).
// ---------------------------------------------------------------------------
__global__ __launch_bounds__(256) void wconv_kernel(
    const float* __restrict__ w0, const float* __restrict__ w1,
    const float* __restrict__ wc,
    __bf16* __restrict__ t0, __bf16* __restrict__ t1, __bf16* __restrict__ tc)
{
    const int z = blockIdx.z;
    const float* W = (z == 0) ? w0 : (z == 1) ? w1 : wc;
    __bf16*      T = (z == 0) ? t0 : (z == 1) ? t1 : tc;

    __shared__ float tile[32][33];
    const int kx = blockIdx.x * 32, nx = blockIdx.y * 32;
    const int tx = threadIdx.x, ty = threadIdx.y;

    for (int i = ty; i < 32; i += 8)
        tile[i][tx] = W[(size_t)(kx + i) * HIDDEN + nx + tx];
    __syncthreads();
    for (int i = ty; i < 32; i += 8)
        T[(size_t)(nx + i) * HIDDEN + kx + tx] = (__bf16)tile[tx][i];
}

// x fp32 -> bf16, 4 elems/thread
__global__ __launch_bounds__(256) void convert_x_kernel(
    const float* __restrict__ x, __bf16* __restrict__ xb)
{
    const size_t i = ((size_t)blockIdx.x * 256 + threadIdx.x) * 4;
    const float4 v = *(const float4*)(x + i);
    bf16x4 o = {(__bf16)v.x, (__bf16)v.y, (__bf16)v.z, (__bf16)v.w};
    *(bf16x4*)(xb + i) = o;
}

// ---------------------------------------------------------------------------
// CSR build: histogram -> 2-level exclusive scan (in-place offs) -> fill
// ---------------------------------------------------------------------------
__global__ __launch_bounds__(256) void hist_kernel(
    const int* __restrict__ dst, int* __restrict__ counts)
{
    int e = blockIdx.x * 256 + threadIdx.x;
    if (e < N_EDGES) atomicAdd(&counts[dst[e]], 1);
}

__device__ __forceinline__ int block_incl_scan(int v, int* s, int t)
{
    s[t] = v; __syncthreads();
    #pragma unroll
    for (int off = 1; off < 256; off <<= 1) {
        int add = (t >= off) ? s[t - off] : 0;
        __syncthreads();
        s[t] += add;
        __syncthreads();
    }
    return s[t];
}

__global__ __launch_bounds__(256) void scan1_kernel(
    const int* __restrict__ counts, int* __restrict__ offs, int* __restrict__ bsum)
{
    __shared__ int s[256];
    const int t = threadIdx.x;
    const int i = blockIdx.x * 256 + t;
    const int v = counts[i];
    int incl = block_incl_scan(v, s, t);
    offs[i] = incl - v;
    if (t == 255) bsum[blockIdx.x] = incl;
}

__global__ __launch_bounds__(256) void scan2_kernel(
    const int* __restrict__ bsum, int* __restrict__ bbase)
{
    __shared__ int s[256];
    const int t = threadIdx.x;
    const int v = (t < SCAN_BLOCKS) ? bsum[t] : 0;
    int incl = block_incl_scan(v, s, t);
    bbase[t] = incl - v;
}

__global__ __launch_bounds__(256) void scan3_kernel(
    int* __restrict__ offs, const int* __restrict__ bbase, int* __restrict__ cursor)
{
    const int i = blockIdx.x * 256 + threadIdx.x;
    const int o = offs[i] + bbase[blockIdx.x];
    offs[i] = o;
    cursor[i] = o;
}

__global__ __launch_bounds__(256) void fill_kernel(
    const int* __restrict__ src, const int* __restrict__ dst,
    int* __restrict__ cursor, int* __restrict__ src_sorted)
{
    int e = blockIdx.x * 256 + threadIdx.x;
    if (e < N_EDGES) {
        int p = atomicAdd(&cursor[dst[e]], 1);
        src_sorted[p] = src[e];
    }
}

// ---------------------------------------------------------------------------
// Pull-mode segment sum, fp32 accumulate, dual-write fp32 + bf16.
// ---------------------------------------------------------------------------
__global__ __launch_bounds__(256) void seg_sum_dual_kernel(
    const float* __restrict__ h,
    const int* __restrict__ srcs,
    const int* __restrict__ offs,
    float* __restrict__ out_f,
    __bf16* __restrict__ out_bf)
{
    const int d = blockIdx.x;
    const int c = threadIdx.x;
    const int beg = offs[d];
    const int end = offs[d + 1];

    float acc = 0.f;
    int j = beg;
    for (; j + 4 <= end; j += 4) {
        const int s0 = srcs[j + 0], s1 = srcs[j + 1];
        const int s2 = srcs[j + 2], s3 = srcs[j + 3];
        const float a0 = h[(size_t)s0 * HIDDEN + c];
        const float a1 = h[(size_t)s1 * HIDDEN + c];
        const float a2 = h[(size_t)s2 * HIDDEN + c];
        const float a3 = h[(size_t)s3 * HIDDEN + c];
        acc += a0 + a1 + a2 + a3;
    }
    for (; j < end; ++j) acc += h[(size_t)srcs[j] * HIDDEN + c];

    out_f[(size_t)d * HIDDEN + c]  = acc;
    out_bf[(size_t)d * HIDDEN + c] = (__bf16)acc;
}

__global__ __launch_bounds__(256) void gather_kernel(
    const float* __restrict__ x,
    const int* __restrict__ pos,
    float* __restrict__ out)
{
    const int i = blockIdx.x;
    const int c = threadIdx.x;
    const int node = pos[i];
    out[(size_t)i * HIDDEN + c] = x[(size_t)node * HIDDEN + c];
}

extern "C" void kernel_launch(void* const* d_in, const int* in_sizes, int n_in,
                              void* d_out, int out_size, void* d_ws, size_t ws_size,
                              hipStream_t stream)
{
    const float* x       = (const float*)d_in[0];
    const float* f0_w    = (const float*)d_in[1];
    const float* f0_b    = (const float*)d_in[2];
    const float* f1_w    = (const float*)d_in[3];
    const float* f1_b    = (const float*)d_in[4];
    const float* conv_w  = (const float*)d_in[5];
    const float* conv_b  = (const float*)d_in[6];
    const int*   edge_src = (const int*)d_in[7];
    const int*   edge_dst = (const int*)d_in[8];
    const int*   pos      = (const int*)d_in[9];
    float* out = (float*)d_out;

    const size_t buf = (size_t)N_NODES * HIDDEN;   // 12.8M elems

    // ws layout (total ~157.6 MB, within the R2-proven footprint)
    char* p = (char*)d_ws;
    __bf16* x_bf  = (__bf16*)p; p += buf * 2;      // 25.6 MB: bf16 x / xnext
    __bf16* x0_bf = (__bf16*)p; p += buf * 2;      // 25.6 MB: bf16 x0
    float*  h     = (float*)p;  p += buf * 4;      // 51.2 MB: conv output
    float*  xf    = (float*)p;  p += buf * 4;      // 51.2 MB: fp32 xnext
    __bf16* wt0   = (__bf16*)p; p += (size_t)HIDDEN * HIDDEN * 2;  // per-layer
    __bf16* wt1   = (__bf16*)p; p += (size_t)HIDDEN * HIDDEN * 2;
    __bf16* wtc   = (__bf16*)p; p += (size_t)HIDDEN * HIDDEN * 2;
    int* counts     = (int*)p;  p += NPAD * 4;     // reused as cursor
    int* offs       = (int*)p;  p += NPAD * 4;
    int* bsum       = (int*)p;  p += 256 * 4;
    int* bbase      = (int*)p;  p += 256 * 4;
    int* src_sorted = (int*)p;  p += (size_t)N_EDGES * 4;
    int* cursor = counts;   // counts dead after scan1

    const int edge_blocks = (N_EDGES + 255) / 256;   // 3125

    // ---- CSR build (edges layer-invariant) ----
    hipMemsetAsync(counts, 0, NPAD * sizeof(int), stream);
    hist_kernel<<<edge_blocks, 256, 0, stream>>>(edge_dst, counts);
    scan1_kernel<<<SCAN_BLOCKS, 256, 0, stream>>>(counts, offs, bsum);
    scan2_kernel<<<1, 256, 0, stream>>>(bsum, bbase);
    scan3_kernel<<<SCAN_BLOCKS, 256, 0, stream>>>(offs, bbase, cursor);
    fill_kernel<<<edge_blocks, 256, 0, stream>>>(edge_src, edge_dst, cursor, src_sorted);

    // ---- x -> bf16 ----
    convert_x_kernel<<<(int)(buf / 4 / 256), 256, 0, stream>>>(x, x_bf);

    const dim3 gemm_grid(391, 2);    // ceil(50000/128) x (256/128)
    const dim3 lbl_grid(64, 2);      // 8192/128 x 2

    for (int l = 0; l < N_LAYERS; ++l) {
        const float* W0 = f0_w   + (size_t)l * HIDDEN * HIDDEN;
        const float* B0 = f0_b   + (size_t)l * HIDDEN;
        const float* W1 = f1_w   + (size_t)l * HIDDEN * HIDDEN;
        const float* B1 = f1_b   + (size_t)l * HIDDEN;
        const float* Wc = conv_w + (size_t)l * HIDDEN * HIDDEN;
        const float* Bc = conv_b + (size_t)l * HIDDEN;

        // transpose+convert this layer's weights to bf16 [n][k]
        wconv_kernel<<<dim3(8, 8, 3), dim3(32, 8), 0, stream>>>(
            W0, W1, Wc, wt0, wt1, wtc);

        // x0 = x @ F0 + b0 (bf16 out)
        mfma_gemm<false, true><<<gemm_grid, 256, 0, stream>>>(
            x_bf, wt0, B0, x0_bf, nullptr, N_NODES);
        // x0[idx] = x[idx] @ F1 + b1 (gather/scatter by idx)
        mfma_gemm<true, true><<<lbl_grid, 256, 0, stream>>>(
            x_bf, wt1, B1, x0_bf, pos, N_LABEL);
        // h = x0 @ Cw + cb (fp32 out for accurate segment sum)
        mfma_gemm<false, false><<<gemm_grid, 256, 0, stream>>>(
            x0_bf, wtc, Bc, h, nullptr, N_NODES);
        // xnext = segment_sum(h[src], dst): fp32 (xf) + bf16 (x_bf, in place)
        seg_sum_dual_kernel<<<N_NODES, 256, 0, stream>>>(
            h, src_sorted, offs, xf, x_bf);
    }

    gather_kernel<<<N_LABEL, 256, 0, stream>>>(xf, pos, out);
}

// Round 4
// 623.058 us; speedup vs baseline: 14.7641x; 1.1347x over previous
//
#include <hip/hip_runtime.h>
#include <hip/hip_bf16.h>

#define N_NODES 50000
#define N_EDGES 800000
#define HIDDEN  256
#define N_LAYERS 3
#define N_PAIRS 4096
#define N_LABEL 8192            // 2*N_PAIRS labeled rows
#define NPAD    50176           // 196*256, padded node count for the scan
#define SCAN_BLOCKS (NPAD / 256) // 196

typedef __bf16 bf16x8 __attribute__((ext_vector_type(8)));
typedef __bf16 bf16x4 __attribute__((ext_vector_type(4)));
typedef float  f32x4  __attribute__((ext_vector_type(4)));

__device__ __forceinline__ void load_lds16(const void* g, void* l) {
    __builtin_amdgcn_global_load_lds(
        (const __attribute__((address_space(1))) void*)g,
        (__attribute__((address_space(3))) void*)l, 16, 0, 0);
}

// ---------------------------------------------------------------------------
// MFMA GEMM: C = A @ Wt^T + bias_term.  A bf16 (rows,256), Wt bf16 [n][k].
// 128x128 tile, BK=32, 4 waves x (4x4) 16x16x32 fragments.
//   GATHER_A : A-rows (and deg lookup) indirect through idx
//   SCATTER_C: C-rows indirect through idx (labeled overwrite; dup-idx benign)
//   DEG_BIAS : bias_term = deg[node]*bias[col]  (conv after aggregation)
//   OUT_BF16 : output dtype
// ---------------------------------------------------------------------------
template <bool GATHER_A, bool SCATTER_C, bool DEG_BIAS, bool OUT_BF16>
__global__ __launch_bounds__(256) void mfma_gemm(
    const __bf16* __restrict__ A,
    const __bf16* __restrict__ Wt,    // (256,256) bf16, Wt[n][k]
    const float* __restrict__ bias,   // (256) fp32
    void* __restrict__ Cout,
    const int* __restrict__ idx,      // row ids if GATHER_A/SCATTER_C
    const int* __restrict__ offs,     // CSR offsets (deg = offs[v+1]-offs[v])
    int M)
{
    __shared__ __bf16 As[128 * 32];   // [row][k] 8 KB
    __shared__ __bf16 Bs[128 * 32];   // [n][k]   8 KB
    __shared__ int s_idx[128];

    const int t    = threadIdx.x;
    const int lane = t & 63;
    const int wave = t >> 6;
    const int m0   = blockIdx.x * 128;
    const int n0   = blockIdx.y * 128;

    if constexpr (GATHER_A || SCATTER_C) {
        if (t < 128) s_idx[t] = idx[m0 + t];
        __syncthreads();
    }

    // staging: chunk c = r*256 + t; row = c>>2, col8 = (c&3)*8
    // LDS dest offset = c*16 bytes (wave-uniform base + lane*16: m104-safe)
    const __bf16* aptr[2];
    const __bf16* bptr[2];
    #pragma unroll
    for (int r = 0; r < 2; ++r) {
        const int c    = r * 256 + t;
        const int row  = c >> 2;
        const int col8 = (c & 3) * 8;
        int node;
        if constexpr (GATHER_A) {
            node = s_idx[row];
        } else {
            const int rg = m0 + row;
            node = (rg < M) ? rg : (M - 1);   // clamp; stores guarded below
        }
        aptr[r] = A  + (size_t)node * HIDDEN + col8;
        bptr[r] = Wt + (size_t)(n0 + row) * HIDDEN + col8;
    }

    f32x4 acc[16];
    #pragma unroll
    for (int i = 0; i < 16; ++i) acc[i] = (f32x4){0.f, 0.f, 0.f, 0.f};

    const int wm   = (wave & 1) * 64;
    const int wn   = (wave >> 1) * 64;
    const int fm   = lane & 15;
    const int quad = lane >> 4;

    for (int k0 = 0; k0 < HIDDEN; k0 += 32) {
        __syncthreads();
        #pragma unroll
        for (int r = 0; r < 2; ++r) {
            load_lds16(aptr[r] + k0, (void*)(As + (size_t)(r * 256 + t) * 8));
            load_lds16(bptr[r] + k0, (void*)(Bs + (size_t)(r * 256 + t) * 8));
        }
        __syncthreads();   // drains vmcnt(0): LDS data visible

        bf16x8 af[4], bfr[4];
        #pragma unroll
        for (int mt = 0; mt < 4; ++mt)
            af[mt] = *(const bf16x8*)(As + (wm + mt * 16 + fm) * 32 + quad * 8);
        #pragma unroll
        for (int nt = 0; nt < 4; ++nt)
            bfr[nt] = *(const bf16x8*)(Bs + (wn + nt * 16 + fm) * 32 + quad * 8);

        #pragma unroll
        for (int mt = 0; mt < 4; ++mt)
            #pragma unroll
            for (int nt = 0; nt < 4; ++nt)
                acc[mt * 4 + nt] = __builtin_amdgcn_mfma_f32_16x16x32_bf16(
                    af[mt], bfr[nt], acc[mt * 4 + nt], 0, 0, 0);
    }

    // epilogue: C/D layout col=lane&15, row=quad*4+reg (m89/m91-verified)
    float bb[4];
    #pragma unroll
    for (int nt = 0; nt < 4; ++nt) bb[nt] = bias[n0 + wn + nt * 16 + fm];

    #pragma unroll
    for (int mt = 0; mt < 4; ++mt) {
        const int rbase = wm + mt * 16 + quad * 4;
        #pragma unroll
        for (int rg = 0; rg < 4; ++rg) {
            const int rloc = rbase + rg;
            int orow;
            if constexpr (SCATTER_C) {
                orow = s_idx[rloc];
            } else {
                orow = m0 + rloc;
                if (orow >= M) continue;
            }
            int node;
            if constexpr (GATHER_A) node = s_idx[rloc];
            else                    node = m0 + rloc;
            float bscale = 1.f;
            if constexpr (DEG_BIAS)
                bscale = (float)(offs[node + 1] - offs[node]);
            #pragma unroll
            for (int nt = 0; nt < 4; ++nt) {
                const int col = n0 + wn + nt * 16 + fm;
                const float v = acc[mt * 4 + nt][rg] + bscale * bb[nt];
                if constexpr (OUT_BF16)
                    ((__bf16*)Cout)[(size_t)orow * HIDDEN + col] = (__bf16)v;
                else
                    ((float*)Cout)[(size_t)orow * HIDDEN + col] = v;
            }
        }
    }
}

// ---------------------------------------------------------------------------
// Weight transpose+convert for one layer: T[n][k] = (bf16)W[k][n], 3 tensors.
// ---------------------------------------------------------------------------
__global__ __launch_bounds__(256) void wconv_kernel(
    const float* __restrict__ w0, const float* __restrict__ w1,
    const float* __restrict__ wc,
    __bf16* __restrict__ t0, __bf16* __restrict__ t1, __bf16* __restrict__ tc)
{
    const int z = blockIdx.z;
    const float* W = (z == 0) ? w0 : (z == 1) ? w1 : wc;
    __bf16*      T = (z == 0) ? t0 : (z == 1) ? t1 : tc;

    __shared__ float tile[32][33];
    const int kx = blockIdx.x * 32, nx = blockIdx.y * 32;
    const int tx = threadIdx.x, ty = threadIdx.y;

    for (int i = ty; i < 32; i += 8)
        tile[i][tx] = W[(size_t)(kx + i) * HIDDEN + nx + tx];
    __syncthreads();
    for (int i = ty; i < 32; i += 8)
        T[(size_t)(nx + i) * HIDDEN + kx + tx] = (__bf16)tile[tx][i];
}

// x fp32 -> bf16, 4 elems/thread
__global__ __launch_bounds__(256) void convert_x_kernel(
    const float* __restrict__ x, __bf16* __restrict__ xb)
{
    const size_t i = ((size_t)blockIdx.x * 256 + threadIdx.x) * 4;
    const float4 v = *(const float4*)(x + i);
    bf16x4 o = {(__bf16)v.x, (__bf16)v.y, (__bf16)v.z, (__bf16)v.w};
    *(bf16x4*)(xb + i) = o;
}

// ---------------------------------------------------------------------------
// CSR build: histogram -> 2-level exclusive scan (in-place offs) -> fill
// ---------------------------------------------------------------------------
__global__ __launch_bounds__(256) void hist_kernel(
    const int* __restrict__ dst, int* __restrict__ counts)
{
    int e = blockIdx.x * 256 + threadIdx.x;
    if (e < N_EDGES) atomicAdd(&counts[dst[e]], 1);
}

__device__ __forceinline__ int block_incl_scan(int v, int* s, int t)
{
    s[t] = v; __syncthreads();
    #pragma unroll
    for (int off = 1; off < 256; off <<= 1) {
        int add = (t >= off) ? s[t - off] : 0;
        __syncthreads();
        s[t] += add;
        __syncthreads();
    }
    return s[t];
}

__global__ __launch_bounds__(256) void scan1_kernel(
    const int* __restrict__ counts, int* __restrict__ offs, int* __restrict__ bsum)
{
    __shared__ int s[256];
    const int t = threadIdx.x;
    const int i = blockIdx.x * 256 + t;
    const int v = counts[i];
    int incl = block_incl_scan(v, s, t);
    offs[i] = incl - v;
    if (t == 255) bsum[blockIdx.x] = incl;
}

__global__ __launch_bounds__(256) void scan2_kernel(
    const int* __restrict__ bsum, int* __restrict__ bbase)
{
    __shared__ int s[256];
    const int t = threadIdx.x;
    const int v = (t < SCAN_BLOCKS) ? bsum[t] : 0;
    int incl = block_incl_scan(v, s, t);
    bbase[t] = incl - v;
}

__global__ __launch_bounds__(256) void scan3_kernel(
    int* __restrict__ offs, const int* __restrict__ bbase, int* __restrict__ cursor)
{
    const int i = blockIdx.x * 256 + threadIdx.x;
    const int o = offs[i] + bbase[blockIdx.x];
    offs[i] = o;
    cursor[i] = o;
}

__global__ __launch_bounds__(256) void fill_kernel(
    const int* __restrict__ src, const int* __restrict__ dst,
    int* __restrict__ cursor, int* __restrict__ src_sorted)
{
    int e = blockIdx.x * 256 + threadIdx.x;
    if (e < N_EDGES) {
        int p = atomicAdd(&cursor[dst[e]], 1);
        src_sorted[p] = src[e];
    }
}

// ---------------------------------------------------------------------------
// Pull-mode bf16 segment sum: out[d] = sum_{j in [offs[d],offs[d+1])} x0[srcs[j]]
// 4 waves/block, one edge per wave per iter; lane loads 8 B (4 bf16 cols).
// fp32 accumulate; cross-wave LDS reduce; bf16 out.
// ---------------------------------------------------------------------------
__global__ __launch_bounds__(256) void seg_sum_bf16_kernel(
    const __bf16* __restrict__ x0,
    const int* __restrict__ srcs,
    const int* __restrict__ offs,
    __bf16* __restrict__ out)
{
    __shared__ float red[4][HIDDEN];   // 4 KB
    const int d    = blockIdx.x;
    const int wave = threadIdx.x >> 6;
    const int lane = threadIdx.x & 63;
    const int beg  = offs[d];
    const int end  = offs[d + 1];

    f32x4 a = (f32x4){0.f, 0.f, 0.f, 0.f};
    for (int j = beg + wave; j < end; j += 4) {
        const int s = srcs[j];    // wave-uniform -> scalar load + broadcast
        const bf16x4 v = *(const bf16x4*)(x0 + (size_t)s * HIDDEN + lane * 4);
        a[0] += (float)v[0]; a[1] += (float)v[1];
        a[2] += (float)v[2]; a[3] += (float)v[3];
    }
    *(f32x4*)&red[wave][lane * 4] = a;
    __syncthreads();

    const int c = threadIdx.x;
    const float s = red[0][c] + red[1][c] + red[2][c] + red[3][c];
    out[(size_t)d * HIDDEN + c] = (__bf16)s;
}

extern "C" void kernel_launch(void* const* d_in, const int* in_sizes, int n_in,
                              void* d_out, int out_size, void* d_ws, size_t ws_size,
                              hipStream_t stream)
{
    const float* x       = (const float*)d_in[0];
    const float* f0_w    = (const float*)d_in[1];
    const float* f0_b    = (const float*)d_in[2];
    const float* f1_w    = (const float*)d_in[3];
    const float* f1_b    = (const float*)d_in[4];
    const float* conv_w  = (const float*)d_in[5];
    const float* conv_b  = (const float*)d_in[6];
    const int*   edge_src = (const int*)d_in[7];
    const int*   edge_dst = (const int*)d_in[8];
    const int*   pos      = (const int*)d_in[9];
    float* out = (float*)d_out;

    const size_t buf = (size_t)N_NODES * HIDDEN;   // 12.8M elems

    char* p = (char*)d_ws;
    __bf16* bufA = (__bf16*)p; p += buf * 2;       // 25.6 MB
    __bf16* bufB = (__bf16*)p; p += buf * 2;       // 25.6 MB
    __bf16* wt0  = (__bf16*)p; p += (size_t)HIDDEN * HIDDEN * 2;
    __bf16* wt1  = (__bf16*)p; p += (size_t)HIDDEN * HIDDEN * 2;
    __bf16* wtc  = (__bf16*)p; p += (size_t)HIDDEN * HIDDEN * 2;
    int* counts     = (int*)p;  p += NPAD * 4;     // reused as cursor
    int* offs       = (int*)p;  p += NPAD * 4;
    int* bsum       = (int*)p;  p += 256 * 4;
    int* bbase      = (int*)p;  p += 256 * 4;
    int* src_sorted = (int*)p;  p += (size_t)N_EDGES * 4;
    int* cursor = counts;       // counts dead after scan1

    const int edge_blocks = (N_EDGES + 255) / 256;   // 3125

    // ---- CSR build (edges layer-invariant) ----
    hipMemsetAsync(counts, 0, NPAD * sizeof(int), stream);
    hist_kernel<<<edge_blocks, 256, 0, stream>>>(edge_dst, counts);
    scan1_kernel<<<SCAN_BLOCKS, 256, 0, stream>>>(counts, offs, bsum);
    scan2_kernel<<<1, 256, 0, stream>>>(bsum, bbase);
    scan3_kernel<<<SCAN_BLOCKS, 256, 0, stream>>>(offs, bbase, cursor);
    fill_kernel<<<edge_blocks, 256, 0, stream>>>(edge_src, edge_dst, cursor, src_sorted);

    // ---- x -> bf16 ----
    convert_x_kernel<<<(int)(buf / 4 / 256), 256, 0, stream>>>(x, bufA);

    const dim3 gemm_grid(391, 2);    // ceil(50000/128) x (256/128)
    const dim3 lbl_grid(64, 2);      // 8192/128 x 2

    __bf16* cur = bufA;              // current x (bf16)
    __bf16* tmp = bufB;

    for (int l = 0; l < N_LAYERS; ++l) {
        const float* W0 = f0_w   + (size_t)l * HIDDEN * HIDDEN;
        const float* B0 = f0_b   + (size_t)l * HIDDEN;
        const float* W1 = f1_w   + (size_t)l * HIDDEN * HIDDEN;
        const float* B1 = f1_b   + (size_t)l * HIDDEN;
        const float* Wc = conv_w + (size_t)l * HIDDEN * HIDDEN;
        const float* Bc = conv_b + (size_t)l * HIDDEN;

        wconv_kernel<<<dim3(8, 8, 3), dim3(32, 8), 0, stream>>>(
            W0, W1, Wc, wt0, wt1, wtc);

        // x0 = x @ F0 + b0  (cur -> tmp)
        mfma_gemm<false, false, false, true><<<gemm_grid, 256, 0, stream>>>(
            cur, wt0, B0, tmp, nullptr, nullptr, N_NODES);
        // x0[idx] = x[idx] @ F1 + b1  (cur -> tmp rows)
        mfma_gemm<true, true, false, true><<<lbl_grid, 256, 0, stream>>>(
            cur, wt1, B1, tmp, pos, nullptr, N_LABEL);
        // s = segment_sum(x0[src])  (tmp -> cur; cur dead after label gemm)
        seg_sum_bf16_kernel<<<N_NODES, 256, 0, stream>>>(
            tmp, src_sorted, offs, cur);

        if (l < N_LAYERS - 1) {
            // x_next = s @ Cw + deg*cb  (cur -> tmp), then swap
            mfma_gemm<false, false, true, true><<<gemm_grid, 256, 0, stream>>>(
                cur, wtc, Bc, tmp, nullptr, offs, N_NODES);
            __bf16* t2 = cur; cur = tmp; tmp = t2;
        } else {
            // out[i] = s[pos[i]] @ Cw + deg[pos[i]]*cb  -> d_out (fp32)
            mfma_gemm<true, false, true, false><<<lbl_grid, 256, 0, stream>>>(
                cur, wtc, Bc, out, pos, offs, N_LABEL);
        }
    }
}

// Round 6
// 482.853 us; speedup vs baseline: 19.0511x; 1.2904x over previous
//
#include <hip/hip_runtime.h>
#include <hip/hip_bf16.h>

#define N_NODES 50000
#define N_EDGES 800000
#define HIDDEN  256
#define N_LAYERS 3
#define N_PAIRS 4096
#define N_LABEL 8192            // 2*N_PAIRS labeled rows
#define NPAD    50176           // 196*256, padded node count for the scan
#define SCAN_BLOCKS (NPAD / 256) // 196

typedef __bf16 bf16x8 __attribute__((ext_vector_type(8)));
typedef __bf16 bf16x4 __attribute__((ext_vector_type(4)));
typedef float  f32x4  __attribute__((ext_vector_type(4)));

__device__ __forceinline__ void load_lds16(const void* g, void* l) {
    __builtin_amdgcn_global_load_lds(
        (const __attribute__((address_space(1))) void*)g,
        (__attribute__((address_space(3))) void*)l, 16, 0, 0);
}

// ---------------------------------------------------------------------------
// MFMA GEMM: C = A @ Wt^T + bias_term.  A bf16 (rows,256), Wt bf16 [n][k].
// 128x128 tile, BK=32, 4 waves x (4x4) 16x16x32 fragments.
//   GATHER_A   : A-rows indirect through idx
//   SCATTER_C  : C-rows indirect through idx (dup-idx writes identical: benign)
//   DEG_BIAS   : bias scaled by deg[node] = offs[node+1]-offs[node]
//   DEG_VIA_IDX: node for deg lookup is idx[row] (A-rows sequential)
//   OUT_BF16   : output dtype
// ---------------------------------------------------------------------------
template <bool GATHER_A, bool SCATTER_C, bool DEG_BIAS, bool DEG_VIA_IDX, bool OUT_BF16>
__global__ __launch_bounds__(256) void mfma_gemm(
    const __bf16* __restrict__ A,
    const __bf16* __restrict__ Wt,    // (256,256) bf16, Wt[n][k]
    const float* __restrict__ bias,   // (256) fp32
    void* __restrict__ Cout,
    const int* __restrict__ idx,
    const int* __restrict__ offs,
    int M)
{
    __shared__ __bf16 As[128 * 32];   // [row][k] 8 KB
    __shared__ __bf16 Bs[128 * 32];   // [n][k]   8 KB
    __shared__ int s_idx[128];

    const int t    = threadIdx.x;
    const int lane = t & 63;
    const int wave = t >> 6;
    const int m0   = blockIdx.x * 128;
    const int n0   = blockIdx.y * 128;

    if constexpr (GATHER_A || SCATTER_C || DEG_VIA_IDX) {
        if (t < 128) s_idx[t] = idx[m0 + t];
        __syncthreads();
    }

    // staging: chunk c = r*256 + t; row = c>>2, col8 = (c&3)*8
    // LDS dest offset = c*16 bytes (wave-uniform base + lane*16: m104-safe)
    const __bf16* aptr[2];
    const __bf16* bptr[2];
    #pragma unroll
    for (int r = 0; r < 2; ++r) {
        const int c    = r * 256 + t;
        const int row  = c >> 2;
        const int col8 = (c & 3) * 8;
        int node;
        if constexpr (GATHER_A) {
            node = s_idx[row];
        } else {
            const int rg = m0 + row;
            node = (rg < M) ? rg : (M - 1);   // clamp; stores guarded below
        }
        aptr[r] = A  + (size_t)node * HIDDEN + col8;
        bptr[r] = Wt + (size_t)(n0 + row) * HIDDEN + col8;
    }

    f32x4 acc[16];
    #pragma unroll
    for (int i = 0; i < 16; ++i) acc[i] = (f32x4){0.f, 0.f, 0.f, 0.f};

    const int wm   = (wave & 1) * 64;
    const int wn   = (wave >> 1) * 64;
    const int fm   = lane & 15;
    const int quad = lane >> 4;

    for (int k0 = 0; k0 < HIDDEN; k0 += 32) {
        __syncthreads();
        #pragma unroll
        for (int r = 0; r < 2; ++r) {
            load_lds16(aptr[r] + k0, (void*)(As + (size_t)(r * 256 + t) * 8));
            load_lds16(bptr[r] + k0, (void*)(Bs + (size_t)(r * 256 + t) * 8));
        }
        __syncthreads();   // drains vmcnt(0): LDS data visible

        bf16x8 af[4], bfr[4];
        #pragma unroll
        for (int mt = 0; mt < 4; ++mt)
            af[mt] = *(const bf16x8*)(As + (wm + mt * 16 + fm) * 32 + quad * 8);
        #pragma unroll
        for (int nt = 0; nt < 4; ++nt)
            bfr[nt] = *(const bf16x8*)(Bs + (wn + nt * 16 + fm) * 32 + quad * 8);

        #pragma unroll
        for (int mt = 0; mt < 4; ++mt)
            #pragma unroll
            for (int nt = 0; nt < 4; ++nt)
                acc[mt * 4 + nt] = __builtin_amdgcn_mfma_f32_16x16x32_bf16(
                    af[mt], bfr[nt], acc[mt * 4 + nt], 0, 0, 0);
    }

    // epilogue: C/D layout col=lane&15, row=quad*4+reg (m89/m91-verified)
    float bb[4];
    #pragma unroll
    for (int nt = 0; nt < 4; ++nt) bb[nt] = bias[n0 + wn + nt * 16 + fm];

    #pragma unroll
    for (int mt = 0; mt < 4; ++mt) {
        const int rbase = wm + mt * 16 + quad * 4;
        #pragma unroll
        for (int rg = 0; rg < 4; ++rg) {
            const int rloc = rbase + rg;
            int orow;
            if constexpr (SCATTER_C) {
                orow = s_idx[rloc];
            } else {
                orow = m0 + rloc;
                if (orow >= M) continue;
            }
            float bscale = 1.f;
            if constexpr (DEG_BIAS) {
                int dnode;
                if constexpr (DEG_VIA_IDX || GATHER_A) dnode = s_idx[rloc];
                else                                   dnode = m0 + rloc;
                bscale = (float)(offs[dnode + 1] - offs[dnode]);
            }
            #pragma unroll
            for (int nt = 0; nt < 4; ++nt) {
                const int col = n0 + wn + nt * 16 + fm;
                const float v = acc[mt * 4 + nt][rg] + bscale * bb[nt];
                if constexpr (OUT_BF16)
                    ((__bf16*)Cout)[(size_t)orow * HIDDEN + col] = (__bf16)v;
                else
                    ((float*)Cout)[(size_t)orow * HIDDEN + col] = v;
            }
        }
    }
}

// ---------------------------------------------------------------------------
// Weight transpose+convert for one layer: T[n][k] = (bf16)W[k][n], 3 tensors.
// ---------------------------------------------------------------------------
__global__ __launch_bounds__(256) void wconv_kernel(
    const float* __restrict__ w0, const float* __restrict__ w1,
    const float* __restrict__ wc,
    __bf16* __restrict__ t0, __bf16* __restrict__ t1, __bf16* __restrict__ tc)
{
    const int z = blockIdx.z;
    const float* W = (z == 0) ? w0 : (z == 1) ? w1 : wc;
    __bf16*      T = (z == 0) ? t0 : (z == 1) ? t1 : tc;

    __shared__ float tile[32][33];
    const int kx = blockIdx.x * 32, nx = blockIdx.y * 32;
    const int tx = threadIdx.x, ty = threadIdx.y;

    for (int i = ty; i < 32; i += 8)
        tile[i][tx] = W[(size_t)(kx + i) * HIDDEN + nx + tx];
    __syncthreads();
    for (int i = ty; i < 32; i += 8)
        T[(size_t)(nx + i) * HIDDEN + kx + tx] = (__bf16)tile[tx][i];
}

// x fp32 -> bf16, 4 elems/thread
__global__ __launch_bounds__(256) void convert_x_kernel(
    const float* __restrict__ x, __bf16* __restrict__ xb)
{
    const size_t i = ((size_t)blockIdx.x * 256 + threadIdx.x) * 4;
    const float4 v = *(const float4*)(x + i);
    bf16x4 o = {(__bf16)v.x, (__bf16)v.y, (__bf16)v.z, (__bf16)v.w};
    *(bf16x4*)(xb + i) = o;
}

// ---------------------------------------------------------------------------
// CSR build: histogram -> 2-level exclusive scan (in-place offs) -> fill
// ---------------------------------------------------------------------------
__global__ __launch_bounds__(256) void hist_kernel(
    const int* __restrict__ dst, int* __restrict__ counts)
{
    int e = blockIdx.x * 256 + threadIdx.x;
    if (e < N_EDGES) atomicAdd(&counts[dst[e]], 1);
}

__device__ __forceinline__ int block_incl_scan(int v, int* s, int t)
{
    s[t] = v; __syncthreads();
    #pragma unroll
    for (int off = 1; off < 256; off <<= 1) {
        int add = (t >= off) ? s[t - off] : 0;
        __syncthreads();
        s[t] += add;
        __syncthreads();
    }
    return s[t];
}

__global__ __launch_bounds__(256) void scan1_kernel(
    const int* __restrict__ counts, int* __restrict__ offs, int* __restrict__ bsum)
{
    __shared__ int s[256];
    const int t = threadIdx.x;
    const int i = blockIdx.x * 256 + t;
    const int v = counts[i];
    int incl = block_incl_scan(v, s, t);
    offs[i] = incl - v;
    if (t == 255) bsum[blockIdx.x] = incl;
}

__global__ __launch_bounds__(256) void scan2_kernel(
    const int* __restrict__ bsum, int* __restrict__ bbase)
{
    __shared__ int s[256];
    const int t = threadIdx.x;
    const int v = (t < SCAN_BLOCKS) ? bsum[t] : 0;
    int incl = block_incl_scan(v, s, t);
    bbase[t] = incl - v;
}

__global__ __launch_bounds__(256) void scan3_kernel(
    int* __restrict__ offs, const int* __restrict__ bbase, int* __restrict__ cursor)
{
    const int i = blockIdx.x * 256 + threadIdx.x;
    const int o = offs[i] + bbase[blockIdx.x];
    offs[i] = o;
    cursor[i] = o;
}

__global__ __launch_bounds__(256) void fill_kernel(
    const int* __restrict__ src, const int* __restrict__ dst,
    int* __restrict__ cursor, int* __restrict__ src_sorted)
{
    int e = blockIdx.x * 256 + threadIdx.x;
    if (e < N_EDGES) {
        int p = atomicAdd(&cursor[dst[e]], 1);
        src_sorted[p] = src[e];
    }
}

// ---------------------------------------------------------------------------
// Pull-mode bf16 segment sum, MLP-optimized:
//  - wave loads 64 src ids in ONE coalesced lane-load, broadcasts via __shfl
//  - half-wave (32 lanes x 16 B) covers one 512 B row -> 2 rows per wave-load
//  - 8 fp32 partials (4 waves x 2 halves) reduced through LDS
// Divergence-safe shfl: trip count uses block-uniform n, so all 64 lanes are
// active at every __shfl (source lane always active; e<64 always). The
// gather/accumulate alone is predicated on e<n.
// COMPACT: node list from nodelist[], output compact rows (blockIdx order).
// ---------------------------------------------------------------------------
template <bool COMPACT>
__global__ __launch_bounds__(256) void seg_sum2_kernel(
    const __bf16* __restrict__ x0,
    const int* __restrict__ srcs,
    const int* __restrict__ offs,
    const int* __restrict__ nodelist,
    __bf16* __restrict__ out)
{
    __shared__ float red[8][HIDDEN];   // 8 KB
    const int b    = blockIdx.x;
    const int d    = COMPACT ? nodelist[b] : b;
    const int t    = threadIdx.x;
    const int wave = t >> 6;
    const int lane = t & 63;
    const int half = lane >> 5;
    const int li   = lane & 31;
    const int beg  = offs[d];
    const int deg  = offs[d + 1] - beg;

    float a[8];
    #pragma unroll
    for (int k = 0; k < 8; ++k) a[k] = 0.f;

    for (int base = 0; base < deg; base += 64) {
        const int n = min(64, deg - base);   // block-uniform
        int vs = 0;
        if (base + lane < deg) vs = srcs[beg + base + lane];
        // uniform trip count over e0; every lane executes every __shfl
        for (int e0 = 0; e0 < n; e0 += 8) {
            const int e = e0 + 2 * wave + half;       // < 64 always
            const int s = __shfl(vs, e);              // all lanes active
            if (e < n) {
                const bf16x8 v = *(const bf16x8*)(x0 + (size_t)s * HIDDEN + li * 8);
                #pragma unroll
                for (int k = 0; k < 8; ++k) a[k] += (float)v[k];
            }
        }
    }

    const int p = wave * 2 + half;     // partial id 0..7
    #pragma unroll
    for (int k = 0; k < 8; ++k) red[p][li * 8 + k] = a[k];
    __syncthreads();

    float s = 0.f;
    #pragma unroll
    for (int r = 0; r < 8; ++r) s += red[r][t];
    out[(size_t)b * HIDDEN + t] = (__bf16)(COMPACT ? s : s);
}

extern "C" void kernel_launch(void* const* d_in, const int* in_sizes, int n_in,
                              void* d_out, int out_size, void* d_ws, size_t ws_size,
                              hipStream_t stream)
{
    const float* x       = (const float*)d_in[0];
    const float* f0_w    = (const float*)d_in[1];
    const float* f0_b    = (const float*)d_in[2];
    const float* f1_w    = (const float*)d_in[3];
    const float* f1_b    = (const float*)d_in[4];
    const float* conv_w  = (const float*)d_in[5];
    const float* conv_b  = (const float*)d_in[6];
    const int*   edge_src = (const int*)d_in[7];
    const int*   edge_dst = (const int*)d_in[8];
    const int*   pos      = (const int*)d_in[9];
    float* out = (float*)d_out;

    const size_t buf = (size_t)N_NODES * HIDDEN;   // 12.8M elems

    char* p = (char*)d_ws;
    __bf16* bufA  = (__bf16*)p; p += buf * 2;      // 25.6 MB
    __bf16* bufB  = (__bf16*)p; p += buf * 2;      // 25.6 MB
    __bf16* s_lbl = (__bf16*)p; p += (size_t)N_LABEL * HIDDEN * 2;  // 4 MB
    __bf16* wt0   = (__bf16*)p; p += (size_t)HIDDEN * HIDDEN * 2;
    __bf16* wt1   = (__bf16*)p; p += (size_t)HIDDEN * HIDDEN * 2;
    __bf16* wtc   = (__bf16*)p; p += (size_t)HIDDEN * HIDDEN * 2;
    int* counts     = (int*)p;  p += NPAD * 4;     // reused as cursor
    int* offs       = (int*)p;  p += NPAD * 4;
    int* bsum       = (int*)p;  p += 256 * 4;
    int* bbase      = (int*)p;  p += 256 * 4;
    int* src_sorted = (int*)p;  p += (size_t)N_EDGES * 4;
    int* cursor = counts;       // counts dead after scan1

    const int edge_blocks = (N_EDGES + 255) / 256;   // 3125

    // ---- CSR build (edges layer-invariant) ----
    hipMemsetAsync(counts, 0, NPAD * sizeof(int), stream);
    hist_kernel<<<edge_blocks, 256, 0, stream>>>(edge_dst, counts);
    scan1_kernel<<<SCAN_BLOCKS, 256, 0, stream>>>(counts, offs, bsum);
    scan2_kernel<<<1, 256, 0, stream>>>(bsum, bbase);
    scan3_kernel<<<SCAN_BLOCKS, 256, 0, stream>>>(offs, bbase, cursor);
    fill_kernel<<<edge_blocks, 256, 0, stream>>>(edge_src, edge_dst, cursor, src_sorted);

    // ---- x -> bf16 ----
    convert_x_kernel<<<(int)(buf / 4 / 256), 256, 0, stream>>>(x, bufA);

    const dim3 gemm_grid(391, 2);    // ceil(50000/128) x (256/128)
    const dim3 lbl_grid(64, 2);      // 8192/128 x 2

    __bf16* cur = bufA;              // current x (bf16)
    __bf16* tmp = bufB;

    for (int l = 0; l < N_LAYERS; ++l) {
        const float* W0 = f0_w   + (size_t)l * HIDDEN * HIDDEN;
        const float* B0 = f0_b   + (size_t)l * HIDDEN;
        const float* W1 = f1_w   + (size_t)l * HIDDEN * HIDDEN;
        const float* B1 = f1_b   + (size_t)l * HIDDEN;
        const float* Wc = conv_w + (size_t)l * HIDDEN * HIDDEN;
        const float* Bc = conv_b + (size_t)l * HIDDEN;

        wconv_kernel<<<dim3(8, 8, 3), dim3(32, 8), 0, stream>>>(
            W0, W1, Wc, wt0, wt1, wtc);

        // x0 = x @ F0 + b0  (cur -> tmp)
        mfma_gemm<false, false, false, false, true><<<gemm_grid, 256, 0, stream>>>(
            cur, wt0, B0, tmp, nullptr, nullptr, N_NODES);
        // x0[idx] = x[idx] @ F1 + b1  (cur -> tmp rows)
        mfma_gemm<true, true, false, false, true><<<lbl_grid, 256, 0, stream>>>(
            cur, wt1, B1, tmp, pos, nullptr, N_LABEL);

        if (l < N_LAYERS - 1) {
            // S = segment_sum(x0[src]) at ALL nodes (tmp -> cur)
            seg_sum2_kernel<false><<<N_NODES, 256, 0, stream>>>(
                tmp, src_sorted, offs, nullptr, cur);
            // x_next = S @ Cw + deg*cb  (cur -> tmp), then swap
            mfma_gemm<false, false, true, false, true><<<gemm_grid, 256, 0, stream>>>(
                cur, wtc, Bc, tmp, nullptr, offs, N_NODES);
            __bf16* t2 = cur; cur = tmp; tmp = t2;
        } else {
            // S only at labeled dst nodes (tmp -> s_lbl, compact pos order)
            seg_sum2_kernel<true><<<N_LABEL, 256, 0, stream>>>(
                tmp, src_sorted, offs, pos, s_lbl);
            // out[i] = S_lbl[i] @ Cw + deg[pos[i]]*cb  -> d_out (fp32)
            mfma_gemm<false, false, true, true, false><<<lbl_grid, 256, 0, stream>>>(
                s_lbl, wtc, Bc, out, pos, offs, N_LABEL);
        }
    }
}